// Round 14
// baseline (211.209 us; speedup 1.0000x reference)
//
#include <hip/hip_runtime.h>

#define HH 256   // H
#define BB 64    // B
#define KK 32    // K
#define LL 64    // L
#define LGRP 8   // l's per edge-kernel block

typedef __bf16 bf16_t;
typedef __attribute__((ext_vector_type(8))) __bf16 bf16x8;
typedef __attribute__((ext_vector_type(4))) float f32x4;

// ---- load 8 contiguous f32, convert to bf16x8 ----
__device__ __forceinline__ bf16x8 ld_a8(const float* __restrict__ p) {
  const f32x4* q = (const f32x4*)p;
  f32x4 a = q[0], b = q[1];
  bf16x8 r;
  r[0] = (__bf16)a[0]; r[1] = (__bf16)a[1]; r[2] = (__bf16)a[2]; r[3] = (__bf16)a[3];
  r[4] = (__bf16)b[0]; r[5] = (__bf16)b[1]; r[6] = (__bf16)b[2]; r[7] = (__bf16)b[3];
  return r;
}
// sum 8 partial slices (stride 524288 f32) -> bf16x8 (loads independent, pipelinable)
__device__ __forceinline__ bf16x8 ld_sum8(const float* __restrict__ p) {
  f32x4 s0 = {0.f,0.f,0.f,0.f}, s1 = s0;
#pragma unroll
  for (int lc = 0; lc < 8; ++lc) {
    const f32x4* q = (const f32x4*)(p + (size_t)lc * 524288);
    s0 += q[0]; s1 += q[1];
  }
  bf16x8 r;
  r[0] = (__bf16)s0[0]; r[1] = (__bf16)s0[1]; r[2] = (__bf16)s0[2]; r[3] = (__bf16)s0[3];
  r[4] = (__bf16)s1[0]; r[5] = (__bf16)s1[1]; r[6] = (__bf16)s1[2]; r[7] = (__bf16)s1[3];
  return r;
}

// ---- e-tile staging (512 threads): 16 f32/thread -> regs -> swizzled bf16 LDS ----
__device__ __forceinline__ void ld_tile(const float* __restrict__ E, int tid, f32x4 r[4]) {
  const f32x4* q = (const f32x4*)(E + tid * 16);
  r[0] = q[0]; r[1] = q[1]; r[2] = q[2]; r[3] = q[3];
}
__device__ __forceinline__ void wr_tile(bf16_t* buf, int tid, const f32x4 r[4]) {
  int row = tid >> 4;
  int colb = (tid & 15) * 32;
  bf16x8 v0, v1;
  v0[0] = (__bf16)r[0][0]; v0[1] = (__bf16)r[0][1]; v0[2] = (__bf16)r[0][2]; v0[3] = (__bf16)r[0][3];
  v0[4] = (__bf16)r[1][0]; v0[5] = (__bf16)r[1][1]; v0[6] = (__bf16)r[1][2]; v0[7] = (__bf16)r[1][3];
  v1[0] = (__bf16)r[2][0]; v1[1] = (__bf16)r[2][1]; v1[2] = (__bf16)r[2][2]; v1[3] = (__bf16)r[2][3];
  v1[4] = (__bf16)r[3][0]; v1[5] = (__bf16)r[3][1]; v1[6] = (__bf16)r[3][2]; v1[7] = (__bf16)r[3][3];
  int swz = (row & 7) << 4;
  *(bf16x8*)((char*)buf + row * 512 + (colb ^ swz)) = v0;
  *(bf16x8*)((char*)buf + row * 512 + ((colb + 16) ^ swz)) = v1;
}

// acc[2][NT] += A(32x256 f32 global)*B(bf16 row-major)^T
template<int LDB, int NT>
__device__ __forceinline__ void mm_f32A(const float* __restrict__ A,
                                        const bf16_t* __restrict__ B,
                                        f32x4 acc[2][NT], int lane) {
  const int c = lane & 15, g = lane >> 4;
#pragma unroll
  for (int ks = 0; ks < 8; ++ks) {
    const int ko = ks * 32 + g * 8;
    bf16x8 a0 = ld_a8(A + (size_t)c * HH + ko);
    bf16x8 a1 = ld_a8(A + (size_t)(16 + c) * HH + ko);
#pragma unroll
    for (int nt = 0; nt < NT; ++nt) {
      bf16x8 bb = *(const bf16x8*)(B + (size_t)(nt * 16 + c) * LDB + ko);
      acc[0][nt] = __builtin_amdgcn_mfma_f32_16x16x32_bf16(a0, bb, acc[0][nt], 0, 0, 0);
      acc[1][nt] = __builtin_amdgcn_mfma_f32_16x16x32_bf16(a1, bb, acc[1][nt], 0, 0, 0);
    }
  }
}

// acc[2][4] += (Σ_lc part)(32x256)*B(bf16)^T — 8-way reduce fused into A-fragments
__device__ __forceinline__ void mm_partA_bf16(const float* __restrict__ P,
                                              const bf16_t* __restrict__ B,
                                              f32x4 acc[2][4], int lane) {
  const int c = lane & 15, g = lane >> 4;
#pragma unroll
  for (int ks = 0; ks < 8; ++ks) {
    const int ko = ks * 32 + g * 8;
    bf16x8 a0 = ld_sum8(P + (size_t)c * HH + ko);
    bf16x8 a1 = ld_sum8(P + (size_t)(16 + c) * HH + ko);
#pragma unroll
    for (int nt = 0; nt < 4; ++nt) {
      bf16x8 bb = *(const bf16x8*)(B + (size_t)(nt * 16 + c) * 256 + ko);
      acc[0][nt] = __builtin_amdgcn_mfma_f32_16x16x32_bf16(a0, bb, acc[0][nt], 0, 0, 0);
      acc[1][nt] = __builtin_amdgcn_mfma_f32_16x16x32_bf16(a1, bb, acc[1][nt], 0, 0, 0);
    }
  }
}

// acc[2][NT] += A(32x256 bf16 LDS, swizzled)*B(bf16 row-major global)^T
template<int LDB, int NT>
__device__ __forceinline__ void mm_ldsA(const bf16_t* lds,
                                        const bf16_t* __restrict__ B,
                                        f32x4 acc[2][NT], int lane) {
  const int c = lane & 15, g = lane >> 4;
  const int swz = (c & 7) << 4;
#pragma unroll
  for (int ks = 0; ks < 8; ++ks) {
    const int kb = (ks * 32 + g * 8) * 2;
    bf16x8 a0 = *(const bf16x8*)((const char*)lds + c * 512 + (kb ^ swz));
    bf16x8 a1 = *(const bf16x8*)((const char*)lds + (16 + c) * 512 + (kb ^ swz));
#pragma unroll
    for (int nt = 0; nt < NT; ++nt) {
      bf16x8 bb = *(const bf16x8*)(B + (size_t)(nt * 16 + c) * LDB + ks * 32 + g * 8);
      acc[0][nt] = __builtin_amdgcn_mfma_f32_16x16x32_bf16(a0, bb, acc[0][nt], 0, 0, 0);
      acc[1][nt] = __builtin_amdgcn_mfma_f32_16x16x32_bf16(a1, bb, acc[1][nt], 0, 0, 0);
    }
  }
}

// ---------------- prep: all weights f32->bf16 (layer-2 msg weights pre-scaled) ----------------
__global__ __launch_bounds__(256) void prep_kernel(
    const float* w0, const float* w1, const float* w2, const float* w3,
    const float* w4, const float* w5, const float* w6, const float* w7,
    const float* w8, const float* w9, bf16_t* wb) {
  int i = blockIdx.x * 256 + threadIdx.x;
  const float* s; int o; float sc = 1.f;
  if      (i < 131072)  { s = w0; o = i; }
  else if (i < 196608)  { s = w1; o = i - 131072; sc = 1.f / 64.f; }   // a2u_w2 / L
  else if (i < 327680)  { s = w2; o = i - 196608; }
  else if (i < 393216)  { s = w3; o = i - 327680; sc = 1.f / 32.f; }   // u2a_w2 / K
  else if (i < 589824)  { s = w4; o = i - 393216; }
  else if (i < 786432)  { s = w5; o = i - 589824; }
  else if (i < 983040)  { s = w6; o = i - 786432; }
  else if (i < 1179648) { s = w7; o = i - 983040; }
  else if (i < 1376256) { s = w8; o = i - 1179648; }
  else                  { s = w9; o = i - 1376256; }
  wb[i] = (__bf16)(s[o] * sc);
}

// ------- fused pair of projections, col-split x2: block covers 128 cols (nt=2) -------
template<int LDW>
__global__ __launch_bounds__(256) void proj2h_kernel(
    const float* __restrict__ X0, const bf16_t* __restrict__ W0,
    const float* __restrict__ b0, float* __restrict__ out0, int n0,
    const float* __restrict__ X1, const bf16_t* __restrict__ W1,
    const float* __restrict__ b1, float* __restrict__ out1) {
  const int t = blockIdx.x >> 1, ch = blockIdx.x & 1;
  const float* X; const bf16_t* W; const float* bias; float* out; int row0;
  if (t < n0) { X = X0; W = W0; bias = b0; out = out0; row0 = t * 32; }
  else        { X = X1; W = W1; bias = b1; out = out1; row0 = (t - n0) * 32; }
  const int tid = threadIdx.x, w = tid >> 6, lane = tid & 63;
  const int colw = ch * 128 + w * 32, c = lane & 15, g = lane >> 4;
  f32x4 acc[2][2];
#pragma unroll
  for (int nt = 0; nt < 2; ++nt) {
    float bv = bias ? bias[colw + nt * 16 + c] : 0.f;
    f32x4 v = {bv, bv, bv, bv};
    acc[0][nt] = v; acc[1][nt] = v;
  }
  mm_f32A<LDW, 2>(X + (size_t)row0 * HH, W + (size_t)colw * LDW, acc, lane);
#pragma unroll
  for (int m = 0; m < 2; ++m)
#pragma unroll
    for (int nt = 0; nt < 2; ++nt)
#pragma unroll
      for (int rr = 0; rr < 4; ++rr) {
        int row = row0 + m * 16 + g * 4 + rr;
        out[(size_t)row * HH + colw + nt * 16 + c] = acc[m][nt][rr];
      }
}

// ---------------- phase A: layer-1 of both message MLPs, relu, reductions ----------------
__global__ __launch_bounds__(512) void phaseA_kernel(
    const float* __restrict__ e, const float* __restrict__ p_ap,
    const float* __restrict__ p_ue,
    const bf16_t* __restrict__ wu1e, const bf16_t* __restrict__ wa1e,
    float* __restrict__ part, float* __restrict__ R_ap) {
  __shared__ bf16_t ebuf[2][32 * 256];
  const int blk = blockIdx.x;              // 512 blocks
  const int b = blk >> 3, lc = blk & 7;
  const int tid = threadIdx.x, w = tid >> 6, lane = tid & 63;
  const int colw = w * 32, c = lane & 15, g = lane >> 4;
  const int l0 = lc * LGRP;

  bf16x8 wU[2][8], wA[2][8];
#pragma unroll
  for (int nt = 0; nt < 2; ++nt)
#pragma unroll
    for (int ks = 0; ks < 8; ++ks) {
      size_t off = (size_t)(colw + nt * 16 + c) * 512 + ks * 32 + g * 8;
      wU[nt][ks] = *(const bf16x8*)(wu1e + off);
      wA[nt][ks] = *(const bf16x8*)(wa1e + off);
    }

  float pue[2][2][4];
#pragma unroll
  for (int m = 0; m < 2; ++m)
#pragma unroll
    for (int nt = 0; nt < 2; ++nt)
#pragma unroll
      for (int rr = 0; rr < 4; ++rr)
        pue[m][nt][rr] = p_ue[(size_t)(b * KK + m * 16 + g * 4 + rr) * HH + colw + nt * 16 + c];

  f32x4 accU[2][2];
  const f32x4 z4 = {0.f, 0.f, 0.f, 0.f};
#pragma unroll
  for (int m = 0; m < 2; ++m)
#pragma unroll
    for (int nt = 0; nt < 2; ++nt) accU[m][nt] = z4;

  f32x4 rs[4];
  ld_tile(e + (size_t)((b * LL + l0) * KK) * HH, tid, rs);
  wr_tile(ebuf[0], tid, rs);

  for (int li = 0; li < LGRP; ++li) {
    __syncthreads();                       // ebuf[li&1] ready; ebuf[(li+1)&1] readers done
    const int l = l0 + li;
    if (li + 1 < LGRP) ld_tile(e + (size_t)((b * LL + l + 1) * KK) * HH, tid, rs);

    f32x4 aU[2][2], aA[2][2];
#pragma unroll
    for (int nt = 0; nt < 2; ++nt) {
      float pa = p_ap[(size_t)(b * LL + l) * HH + colw + nt * 16 + c];
      f32x4 t = {pa, pa, pa, pa};
      aA[0][nt] = t; aA[1][nt] = t;
#pragma unroll
      for (int rr = 0; rr < 4; ++rr) {
        aU[0][nt][rr] = pue[0][nt][rr];
        aU[1][nt][rr] = pue[1][nt][rr];
      }
    }
    const bf16_t* eb = ebuf[li & 1];
    const int swz = (c & 7) << 4;
#pragma unroll
    for (int ks = 0; ks < 8; ++ks) {
      const int kb = (ks * 32 + g * 8) * 2;
      bf16x8 a0 = *(const bf16x8*)((const char*)eb + c * 512 + (kb ^ swz));
      bf16x8 a1 = *(const bf16x8*)((const char*)eb + (16 + c) * 512 + (kb ^ swz));
#pragma unroll
      for (int nt = 0; nt < 2; ++nt) {
        aU[0][nt] = __builtin_amdgcn_mfma_f32_16x16x32_bf16(a0, wU[nt][ks], aU[0][nt], 0, 0, 0);
        aU[1][nt] = __builtin_amdgcn_mfma_f32_16x16x32_bf16(a1, wU[nt][ks], aU[1][nt], 0, 0, 0);
        aA[0][nt] = __builtin_amdgcn_mfma_f32_16x16x32_bf16(a0, wA[nt][ks], aA[0][nt], 0, 0, 0);
        aA[1][nt] = __builtin_amdgcn_mfma_f32_16x16x32_bf16(a1, wA[nt][ks], aA[1][nt], 0, 0, 0);
      }
    }

    // u2a: relu + k-reduce -> R_ap[b,l,:]
#pragma unroll
    for (int nt = 0; nt < 2; ++nt) {
      float s = 0.f;
#pragma unroll
      for (int m = 0; m < 2; ++m)
#pragma unroll
        for (int rr = 0; rr < 4; ++rr) s += fmaxf(aU[m][nt][rr], 0.f);
      s += __shfl_xor(s, 16);
      s += __shfl_xor(s, 32);
      if (lane < 16)
        R_ap[(size_t)(b * LL + l) * HH + colw + nt * 16 + lane] = s;
    }
    // a2u: relu accumulate over l
#pragma unroll
    for (int m = 0; m < 2; ++m)
#pragma unroll
      for (int nt = 0; nt < 2; ++nt)
#pragma unroll
        for (int rr = 0; rr < 4; ++rr)
          accU[m][nt][rr] += fmaxf(aA[m][nt][rr], 0.f);

    if (li + 1 < LGRP) wr_tile(ebuf[(li + 1) & 1], tid, rs);
  }

#pragma unroll
  for (int m = 0; m < 2; ++m)
#pragma unroll
    for (int nt = 0; nt < 2; ++nt)
#pragma unroll
      for (int rr = 0; rr < 4; ++rr) {
        int krow = m * 16 + g * 4 + rr;
        part[(size_t)((lc * BB + b) * KK + krow) * HH + colw + nt * 16 + c] = accU[m][nt][rr];
      }
}

// ======== node2: (8-way reduce +) m-GEMM + GRU + q-GEMM fused, all B operands bf16 ========
// 192 blocks (64 UE + 128 AP), 256 threads. UE stage-1 sums part slices in A-fragments
// (ld_sum8 + bf16 B — the untried cell; R7/R8 slowness co-occurred with f32-B cvt).
__global__ __launch_bounds__(256) void node2_kernel(
    const float* __restrict__ part, const float* __restrict__ R_ap,
    const bf16_t* __restrict__ wa2s, const float* __restrict__ a2u_b2,
    const bf16_t* __restrict__ wu2s, const float* __restrict__ u2a_b2,
    const float* __restrict__ h_ue, const bf16_t* __restrict__ wih_ue,
    const float* __restrict__ ue_bih, const bf16_t* __restrict__ whh_ue,
    const float* __restrict__ ue_bhh,
    const float* __restrict__ h_ap, const bf16_t* __restrict__ wih_ap,
    const float* __restrict__ ap_bih, const bf16_t* __restrict__ whh_ap,
    const float* __restrict__ ap_bhh,
    const bf16_t* __restrict__ wed1, const float* __restrict__ ed_b1,
    float* __restrict__ hue_new, float* __restrict__ hap_new,
    float* __restrict__ q_ue, float* __restrict__ q_ap) {
  __shared__ bf16_t mbuf[32 * 256];
  __shared__ bf16_t hbuf[32 * 256];
  const int blk = blockIdx.x;
  const bool ue = blk < 64;
  const int row0 = ue ? blk * 32 : (blk - 64) * 32;
  const int tid = threadIdx.x, w = tid >> 6, lane = tid & 63;
  const int colw = w * 64, c = lane & 15, g = lane >> 4;
  const bf16_t* W2  = ue ? wa2s : wu2s;
  const float*  b2  = ue ? a2u_b2 : u2a_b2;
  const float*  h   = ue ? h_ue : h_ap;
  const bf16_t* wih = ue ? wih_ue : wih_ap;
  const bf16_t* whh = ue ? whh_ue : whh_ap;
  const float*  bih = ue ? ue_bih : ap_bih;
  const float*  bhh = ue ? ue_bhh : ap_bhh;
  float* hout = ue ? hue_new : hap_new;
  float* qout = ue ? q_ue : q_ap;
  const bf16_t* wq = wed1 + (ue ? 0 : 256);   // Wed1[:, :H] vs Wed1[:, H:2H]

  // ---- stage 1: m = R*(W2*sc)^T + b2 -> mbuf (swizzled bf16) ----
  f32x4 acc[2][4];
#pragma unroll
  for (int nt = 0; nt < 4; ++nt) {
    float bv = b2[colw + nt * 16 + c];
    f32x4 t = {bv, bv, bv, bv};
    acc[0][nt] = t; acc[1][nt] = t;
  }
  if (ue) mm_partA_bf16(part + (size_t)row0 * HH, W2 + (size_t)colw * 256, acc, lane);
  else    mm_f32A<256, 4>(R_ap + (size_t)row0 * HH, W2 + (size_t)colw * 256, acc, lane);
#pragma unroll
  for (int m = 0; m < 2; ++m)
#pragma unroll
    for (int nt = 0; nt < 4; ++nt)
#pragma unroll
      for (int rr = 0; rr < 4; ++rr) {
        int row = m * 16 + g * 4 + rr;
        int col = colw + nt * 16 + c;
        int off = row * 512 + ((col * 2) ^ ((row & 7) << 4));
        *(bf16_t*)((char*)mbuf + off) = (__bf16)acc[m][nt][rr];
      }
  __syncthreads();

  // ---- stage 2: GRU (x from mbuf LDS, h from global, weights bf16) ----
  f32x4 aR[2][4], aZ[2][4], aN[2][4], aHN[2][4];
#pragma unroll
  for (int nt = 0; nt < 4; ++nt) {
    int col = colw + nt * 16 + c;
    float vR = bih[col] + bhh[col];
    float vZ = bih[256 + col] + bhh[256 + col];
    float vN = bih[512 + col];
    float vH = bhh[512 + col];
    f32x4 tR = {vR, vR, vR, vR}, tZ = {vZ, vZ, vZ, vZ};
    f32x4 tN = {vN, vN, vN, vN}, tH = {vH, vH, vH, vH};
    aR[0][nt] = tR; aR[1][nt] = tR;
    aZ[0][nt] = tZ; aZ[1][nt] = tZ;
    aN[0][nt] = tN; aN[1][nt] = tN;
    aHN[0][nt] = tH; aHN[1][nt] = tH;
  }
  const float* Hp = h + (size_t)row0 * HH;
  mm_ldsA<256, 4>(mbuf, wih + (size_t)(0   + colw) * 256, aR, lane);
  mm_f32A<256, 4>(Hp,  whh + (size_t)(0   + colw) * 256, aR, lane);
  mm_ldsA<256, 4>(mbuf, wih + (size_t)(256 + colw) * 256, aZ, lane);
  mm_f32A<256, 4>(Hp,  whh + (size_t)(256 + colw) * 256, aZ, lane);
  mm_ldsA<256, 4>(mbuf, wih + (size_t)(512 + colw) * 256, aN, lane);
  mm_f32A<256, 4>(Hp,  whh + (size_t)(512 + colw) * 256, aHN, lane);
#pragma unroll
  for (int m = 0; m < 2; ++m)
#pragma unroll
    for (int nt = 0; nt < 4; ++nt)
#pragma unroll
      for (int rr = 0; rr < 4; ++rr) {
        int row = m * 16 + g * 4 + rr;
        int col = colw + nt * 16 + c;
        float rg = 1.f / (1.f + __expf(-aR[m][nt][rr]));
        float zg = 1.f / (1.f + __expf(-aZ[m][nt][rr]));
        float tv = aN[m][nt][rr] + rg * aHN[m][nt][rr];
        tv = fminf(fmaxf(tv, -15.f), 15.f);
        float ex = __expf(-2.f * tv);
        float ng = (1.f - ex) / (1.f + ex);
        float ho = h[(size_t)(row0 + row) * HH + col];
        float hn = (1.f - zg) * ng + zg * ho;
        hout[(size_t)(row0 + row) * HH + col] = hn;
        int off = row * 512 + ((col * 2) ^ ((row & 7) << 4));
        *(bf16_t*)((char*)hbuf + off) = (__bf16)hn;
      }
  __syncthreads();

  // ---- stage 3: q = h_new(LDS) * Wed1_part^T (+ ed_b1 for UE) ----
  f32x4 aq[2][4];
#pragma unroll
  for (int nt = 0; nt < 4; ++nt) {
    float bv = ue ? ed_b1[colw + nt * 16 + c] : 0.f;
    f32x4 t = {bv, bv, bv, bv};
    aq[0][nt] = t; aq[1][nt] = t;
  }
  mm_ldsA<768, 4>(hbuf, wq + (size_t)colw * 768, aq, lane);
#pragma unroll
  for (int m = 0; m < 2; ++m)
#pragma unroll
    for (int nt = 0; nt < 4; ++nt)
#pragma unroll
      for (int rr = 0; rr < 4; ++rr) {
        int row = row0 + m * 16 + g * 4 + rr;
        qout[(size_t)row * HH + colw + nt * 16 + c] = aq[m][nt][rr];
      }
}

// ---------------- phase C: edge update, software-pipelined two-GEMM chain (R11) ----------------
__global__ __launch_bounds__(512) void phaseC_kernel(
    const float* __restrict__ e, const float* __restrict__ q_ue,
    const float* __restrict__ q_ap,
    const bf16_t* __restrict__ wed1e, const bf16_t* __restrict__ wed2,
    const float* __restrict__ ed_b2, float* __restrict__ e_new) {
  __shared__ bf16_t ebuf[2][32 * 256];
  __shared__ bf16_t pbuf[2][32 * 256];
  const int blk = blockIdx.x;              // 512 blocks
  const int b = blk >> 3, lc = blk & 7;
  const int tid = threadIdx.x, w = tid >> 6, lane = tid & 63;
  const int colw = w * 32, c = lane & 15, g = lane >> 4;
  const int l0 = lc * LGRP;

  bf16x8 w1[2][8], w2[2][8];
#pragma unroll
  for (int nt = 0; nt < 2; ++nt)
#pragma unroll
    for (int ks = 0; ks < 8; ++ks) {
      w1[nt][ks] = *(const bf16x8*)(wed1e + (size_t)(colw + nt * 16 + c) * 768 + ks * 32 + g * 8);
      w2[nt][ks] = *(const bf16x8*)(wed2  + (size_t)(colw + nt * 16 + c) * 256 + ks * 32 + g * 8);
    }

  float qU[2][2][4];
#pragma unroll
  for (int m = 0; m < 2; ++m)
#pragma unroll
    for (int nt = 0; nt < 2; ++nt)
#pragma unroll
      for (int rr = 0; rr < 4; ++rr)
        qU[m][nt][rr] = q_ue[(size_t)(b * KK + m * 16 + g * 4 + rr) * HH + colw + nt * 16 + c];
  float b2v[2];
#pragma unroll
  for (int nt = 0; nt < 2; ++nt) b2v[nt] = ed_b2[colw + nt * 16 + c];

  const int swz = (c & 7) << 4;

  f32x4 rs[4];
  ld_tile(e + (size_t)((b * LL + l0) * KK) * HH, tid, rs);
  wr_tile(ebuf[0], tid, rs);

  for (int li = 0; li < LGRP; ++li) {
    __syncthreads();   // ebuf[li&1] + pbuf[(li-1)&1] ready; pbuf[li&1]/ebuf[(li+1)&1] readers done
    const int l = l0 + li;
    if (li + 1 < LGRP) ld_tile(e + (size_t)((b * LL + l + 1) * KK) * HH, tid, rs);

    // ---- layer-2 for tile li-1 (pbuf[(li-1)&1]) -> e_new[l-1] ----
    if (li > 0) {
      const bf16_t* pb = pbuf[(li - 1) & 1];
      f32x4 a2[2][2];
#pragma unroll
      for (int nt = 0; nt < 2; ++nt) {
        f32x4 t = {b2v[nt], b2v[nt], b2v[nt], b2v[nt]};
        a2[0][nt] = t; a2[1][nt] = t;
      }
#pragma unroll
      for (int ks = 0; ks < 8; ++ks) {
        const int kb = (ks * 32 + g * 8) * 2;
        bf16x8 a0 = *(const bf16x8*)((const char*)pb + c * 512 + (kb ^ swz));
        bf16x8 a1f = *(const bf16x8*)((const char*)pb + (16 + c) * 512 + (kb ^ swz));
#pragma unroll
        for (int nt = 0; nt < 2; ++nt) {
          a2[0][nt] = __builtin_amdgcn_mfma_f32_16x16x32_bf16(a0,  w2[nt][ks], a2[0][nt], 0, 0, 0);
          a2[1][nt] = __builtin_amdgcn_mfma_f32_16x16x32_bf16(a1f, w2[nt][ks], a2[1][nt], 0, 0, 0);
        }
      }
#pragma unroll
      for (int m = 0; m < 2; ++m)
#pragma unroll
        for (int nt = 0; nt < 2; ++nt)
#pragma unroll
          for (int rr = 0; rr < 4; ++rr) {
            int row = m * 16 + g * 4 + rr;
            int col = colw + nt * 16 + c;
            e_new[(size_t)((b * LL + l - 1) * KK + row) * HH + col] = a2[m][nt][rr];
          }
    }

    // ---- layer-1 for tile li (ebuf[li&1]) -> relu -> pbuf[li&1] ----
    f32x4 a1[2][2];
#pragma unroll
    for (int nt = 0; nt < 2; ++nt) {
      float qa = q_ap[(size_t)(b * LL + l) * HH + colw + nt * 16 + c];
#pragma unroll
      for (int rr = 0; rr < 4; ++rr) {
        a1[0][nt][rr] = qa + qU[0][nt][rr];
        a1[1][nt][rr] = qa + qU[1][nt][rr];
      }
    }
    const bf16_t* eb = ebuf[li & 1];
#pragma unroll
    for (int ks = 0; ks < 8; ++ks) {
      const int kb = (ks * 32 + g * 8) * 2;
      bf16x8 a0 = *(const bf16x8*)((const char*)eb + c * 512 + (kb ^ swz));
      bf16x8 a1f = *(const bf16x8*)((const char*)eb + (16 + c) * 512 + (kb ^ swz));
#pragma unroll
      for (int nt = 0; nt < 2; ++nt) {
        a1[0][nt] = __builtin_amdgcn_mfma_f32_16x16x32_bf16(a0,  w1[nt][ks], a1[0][nt], 0, 0, 0);
        a1[1][nt] = __builtin_amdgcn_mfma_f32_16x16x32_bf16(a1f, w1[nt][ks], a1[1][nt], 0, 0, 0);
      }
    }
    bf16_t* pw = pbuf[li & 1];
#pragma unroll
    for (int m = 0; m < 2; ++m)
#pragma unroll
      for (int nt = 0; nt < 2; ++nt)
#pragma unroll
        for (int rr = 0; rr < 4; ++rr) {
          int row = m * 16 + g * 4 + rr;
          int col = colw + nt * 16 + c;
          float v = fmaxf(a1[m][nt][rr], 0.f);
          int off = row * 512 + ((col * 2) ^ ((row & 7) << 4));
          *(bf16_t*)((char*)pw + off) = (__bf16)v;
        }

    if (li + 1 < LGRP) wr_tile(ebuf[(li + 1) & 1], tid, rs);
  }

  // ---- epilogue: layer-2 for the last tile ----
  __syncthreads();
  {
    const bf16_t* pb = pbuf[(LGRP - 1) & 1];
    f32x4 a2[2][2];
#pragma unroll
    for (int nt = 0; nt < 2; ++nt) {
      f32x4 t = {b2v[nt], b2v[nt], b2v[nt], b2v[nt]};
      a2[0][nt] = t; a2[1][nt] = t;
    }
#pragma unroll
    for (int ks = 0; ks < 8; ++ks) {
      const int kb = (ks * 32 + g * 8) * 2;
      bf16x8 a0 = *(const bf16x8*)((const char*)pb + c * 512 + (kb ^ swz));
      bf16x8 a1f = *(const bf16x8*)((const char*)pb + (16 + c) * 512 + (kb ^ swz));
#pragma unroll
      for (int nt = 0; nt < 2; ++nt) {
        a2[0][nt] = __builtin_amdgcn_mfma_f32_16x16x32_bf16(a0,  w2[nt][ks], a2[0][nt], 0, 0, 0);
        a2[1][nt] = __builtin_amdgcn_mfma_f32_16x16x32_bf16(a1f, w2[nt][ks], a2[1][nt], 0, 0, 0);
      }
    }
#pragma unroll
    for (int m = 0; m < 2; ++m)
#pragma unroll
      for (int nt = 0; nt < 2; ++nt)
#pragma unroll
        for (int rr = 0; rr < 4; ++rr) {
          int row = m * 16 + g * 4 + rr;
          int col = colw + nt * 16 + c;
          e_new[(size_t)((b * LL + l0 + LGRP - 1) * KK + row) * HH + col] = a2[m][nt][rr];
        }
  }
}

extern "C" void kernel_launch(void* const* d_in, const int* in_sizes, int n_in,
                              void* d_out, int out_size, void* d_ws, size_t ws_size,
                              hipStream_t stream) {
  const float* h_ue   = (const float*)d_in[0];
  const float* h_ap   = (const float*)d_in[1];
  const float* e      = (const float*)d_in[2];
  const float* a2u_w1 = (const float*)d_in[3];
  const float* a2u_b1 = (const float*)d_in[4];
  const float* a2u_w2 = (const float*)d_in[5];
  const float* a2u_b2 = (const float*)d_in[6];
  const float* u2a_w1 = (const float*)d_in[7];
  const float* u2a_b1 = (const float*)d_in[8];
  const float* u2a_w2 = (const float*)d_in[9];
  const float* u2a_b2 = (const float*)d_in[10];
  const float* ue_wih = (const float*)d_in[11];
  const float* ue_bih = (const float*)d_in[12];
  const float* ue_whh = (const float*)d_in[13];
  const float* ue_bhh = (const float*)d_in[14];
  const float* ap_wih = (const float*)d_in[15];
  const float* ap_bih = (const float*)d_in[16];
  const float* ap_whh = (const float*)d_in[17];
  const float* ap_bhh = (const float*)d_in[18];
  const float* ed_w1  = (const float*)d_in[19];
  const float* ed_b1  = (const float*)d_in[20];
  const float* ed_w2  = (const float*)d_in[21];
  const float* ed_b2  = (const float*)d_in[22];

  // workspace layout (bf16 weights, then f32 scratch)
  bf16_t* wb      = (bf16_t*)d_ws;
  bf16_t* wa1     = wb;                 // a2u_w1 (256x512)
  bf16_t* wa2s    = wa1 + 131072;       // a2u_w2 / 64
  bf16_t* wu1     = wa2s + 65536;       // u2a_w1 (256x512)
  bf16_t* wu2s    = wu1 + 131072;       // u2a_w2 / 32
  bf16_t* wih_ue  = wu2s + 65536;
  bf16_t* whh_ue  = wih_ue + 196608;
  bf16_t* wih_ap  = whh_ue + 196608;
  bf16_t* whh_ap  = wih_ap + 196608;
  bf16_t* wed1    = whh_ap + 196608;    // ed_w1 (256x768)
  bf16_t* wed2    = wed1 + 196608;      // ed_w2 (256x256)
  float* fbase = (float*)((char*)d_ws + 2883584);
  float* p_ap = fbase + 1572864;        // 1048576
  float* p_ue = p_ap + 1048576;         // 524288
  float* q_ue = p_ue + 524288;          // 524288
  float* q_ap = q_ue + 524288;          // 1048576 (aliased: R_ap before node2)
  float* part = q_ap + 1048576;         // 8 * 524288
  float* R_ap = q_ap;                   // node2 reads R_ap rows (stage 1), writes q_ap rows (stage 3) — safe

  float* out      = (float*)d_out;
  float* hue_new  = out;                // 524288
  float* hap_new  = out + 524288;       // 1048576
  float* e_new    = out + 1572864;      // 33554432

  prep_kernel<<<5632, 256, 0, stream>>>(a2u_w1, a2u_w2, u2a_w1, u2a_w2,
                                        ue_wih, ue_whh, ap_wih, ap_whh,
                                        ed_w1, ed_w2, wb);
  // p_ap = h_ap*Wa1_h^T + b1 ; p_ue = h_ue*Wu1_h^T + b1
  proj2h_kernel<512><<<384, 256, 0, stream>>>(h_ap, wa1, a2u_b1, p_ap, 128,
                                              h_ue, wu1, u2a_b1, p_ue);
  phaseA_kernel<<<512, 512, 0, stream>>>(e, p_ap, p_ue, wu1 + 256, wa1 + 256,
                                         part, R_ap);
  node2_kernel<<<192, 256, 0, stream>>>(part, R_ap,
                                        wa2s, a2u_b2, wu2s, u2a_b2,
                                        h_ue, wih_ue, ue_bih, whh_ue, ue_bhh,
                                        h_ap, wih_ap, ap_bih, whh_ap, ap_bhh,
                                        wed1, ed_b1,
                                        hue_new, hap_new, q_ue, q_ap);
  phaseC_kernel<<<512, 512, 0, stream>>>(e, q_ue, q_ap, wed1 + 512, wed2, ed_b2, e_new);
}

// Round 15
// 197.359 us; speedup vs baseline: 1.0702x; 1.0702x over previous
//
#include <hip/hip_runtime.h>

#define HH 256   // H
#define BB 64    // B
#define KK 32    // K
#define LL 64    // L
#define LGRP 8   // l's per edge-kernel block

typedef __bf16 bf16_t;
typedef __attribute__((ext_vector_type(8))) __bf16 bf16x8;
typedef __attribute__((ext_vector_type(4))) float f32x4;

// ---- load 8 contiguous f32, convert to bf16x8 ----
__device__ __forceinline__ bf16x8 ld_a8(const float* __restrict__ p) {
  const f32x4* q = (const f32x4*)p;
  f32x4 a = q[0], b = q[1];
  bf16x8 r;
  r[0] = (__bf16)a[0]; r[1] = (__bf16)a[1]; r[2] = (__bf16)a[2]; r[3] = (__bf16)a[3];
  r[4] = (__bf16)b[0]; r[5] = (__bf16)b[1]; r[6] = (__bf16)b[2]; r[7] = (__bf16)b[3];
  return r;
}

// ---- e-tile staging (512 threads): 16 f32/thread -> regs -> swizzled bf16 LDS ----
__device__ __forceinline__ void ld_tile(const float* __restrict__ E, int tid, f32x4 r[4]) {
  const f32x4* q = (const f32x4*)(E + tid * 16);
  r[0] = q[0]; r[1] = q[1]; r[2] = q[2]; r[3] = q[3];
}
__device__ __forceinline__ void wr_tile(bf16_t* buf, int tid, const f32x4 r[4]) {
  int row = tid >> 4;
  int colb = (tid & 15) * 32;
  bf16x8 v0, v1;
  v0[0] = (__bf16)r[0][0]; v0[1] = (__bf16)r[0][1]; v0[2] = (__bf16)r[0][2]; v0[3] = (__bf16)r[0][3];
  v0[4] = (__bf16)r[1][0]; v0[5] = (__bf16)r[1][1]; v0[6] = (__bf16)r[1][2]; v0[7] = (__bf16)r[1][3];
  v1[0] = (__bf16)r[2][0]; v1[1] = (__bf16)r[2][1]; v1[2] = (__bf16)r[2][2]; v1[3] = (__bf16)r[2][3];
  v1[4] = (__bf16)r[3][0]; v1[5] = (__bf16)r[3][1]; v1[6] = (__bf16)r[3][2]; v1[7] = (__bf16)r[3][3];
  int swz = (row & 7) << 4;
  *(bf16x8*)((char*)buf + row * 512 + (colb ^ swz)) = v0;
  *(bf16x8*)((char*)buf + row * 512 + ((colb + 16) ^ swz)) = v1;
}

// acc[2][NT] += A(32x256 f32 global)*B(bf16 row-major)^T
template<int LDB, int NT>
__device__ __forceinline__ void mm_f32A(const float* __restrict__ A,
                                        const bf16_t* __restrict__ B,
                                        f32x4 acc[2][NT], int lane) {
  const int c = lane & 15, g = lane >> 4;
#pragma unroll
  for (int ks = 0; ks < 8; ++ks) {
    const int ko = ks * 32 + g * 8;
    bf16x8 a0 = ld_a8(A + (size_t)c * HH + ko);
    bf16x8 a1 = ld_a8(A + (size_t)(16 + c) * HH + ko);
#pragma unroll
    for (int nt = 0; nt < NT; ++nt) {
      bf16x8 bb = *(const bf16x8*)(B + (size_t)(nt * 16 + c) * LDB + ko);
      acc[0][nt] = __builtin_amdgcn_mfma_f32_16x16x32_bf16(a0, bb, acc[0][nt], 0, 0, 0);
      acc[1][nt] = __builtin_amdgcn_mfma_f32_16x16x32_bf16(a1, bb, acc[1][nt], 0, 0, 0);
    }
  }
}

// acc[2][NT] += A(32x256 bf16 LDS, swizzled)*B(bf16 row-major global)^T
template<int LDB, int NT>
__device__ __forceinline__ void mm_ldsA(const bf16_t* lds,
                                        const bf16_t* __restrict__ B,
                                        f32x4 acc[2][NT], int lane) {
  const int c = lane & 15, g = lane >> 4;
  const int swz = (c & 7) << 4;
#pragma unroll
  for (int ks = 0; ks < 8; ++ks) {
    const int kb = (ks * 32 + g * 8) * 2;
    bf16x8 a0 = *(const bf16x8*)((const char*)lds + c * 512 + (kb ^ swz));
    bf16x8 a1 = *(const bf16x8*)((const char*)lds + (16 + c) * 512 + (kb ^ swz));
#pragma unroll
    for (int nt = 0; nt < NT; ++nt) {
      bf16x8 bb = *(const bf16x8*)(B + (size_t)(nt * 16 + c) * LDB + ks * 32 + g * 8);
      acc[0][nt] = __builtin_amdgcn_mfma_f32_16x16x32_bf16(a0, bb, acc[0][nt], 0, 0, 0);
      acc[1][nt] = __builtin_amdgcn_mfma_f32_16x16x32_bf16(a1, bb, acc[1][nt], 0, 0, 0);
    }
  }
}

// ---------------- prep: all weights f32->bf16 (layer-2 msg weights pre-scaled) ----------------
__global__ __launch_bounds__(256) void prep_kernel(
    const float* w0, const float* w1, const float* w2, const float* w3,
    const float* w4, const float* w5, const float* w6, const float* w7,
    const float* w8, const float* w9, bf16_t* wb) {
  int i = blockIdx.x * 256 + threadIdx.x;
  const float* s; int o; float sc = 1.f;
  if      (i < 131072)  { s = w0; o = i; }
  else if (i < 196608)  { s = w1; o = i - 131072; sc = 1.f / 64.f; }   // a2u_w2 / L
  else if (i < 327680)  { s = w2; o = i - 196608; }
  else if (i < 393216)  { s = w3; o = i - 327680; sc = 1.f / 32.f; }   // u2a_w2 / K
  else if (i < 589824)  { s = w4; o = i - 393216; }
  else if (i < 786432)  { s = w5; o = i - 589824; }
  else if (i < 983040)  { s = w6; o = i - 786432; }
  else if (i < 1179648) { s = w7; o = i - 983040; }
  else if (i < 1376256) { s = w8; o = i - 1179648; }
  else                  { s = w9; o = i - 1376256; }
  wb[i] = (__bf16)(s[o] * sc);
}

// ------- fused pair of projections, col-split x2: block covers 128 cols (nt=2) -------
template<int LDW>
__global__ __launch_bounds__(256) void proj2h_kernel(
    const float* __restrict__ X0, const bf16_t* __restrict__ W0,
    const float* __restrict__ b0, float* __restrict__ out0, int n0,
    const float* __restrict__ X1, const bf16_t* __restrict__ W1,
    const float* __restrict__ b1, float* __restrict__ out1) {
  const int t = blockIdx.x >> 1, ch = blockIdx.x & 1;
  const float* X; const bf16_t* W; const float* bias; float* out; int row0;
  if (t < n0) { X = X0; W = W0; bias = b0; out = out0; row0 = t * 32; }
  else        { X = X1; W = W1; bias = b1; out = out1; row0 = (t - n0) * 32; }
  const int tid = threadIdx.x, w = tid >> 6, lane = tid & 63;
  const int colw = ch * 128 + w * 32, c = lane & 15, g = lane >> 4;
  f32x4 acc[2][2];
#pragma unroll
  for (int nt = 0; nt < 2; ++nt) {
    float bv = bias ? bias[colw + nt * 16 + c] : 0.f;
    f32x4 v = {bv, bv, bv, bv};
    acc[0][nt] = v; acc[1][nt] = v;
  }
  mm_f32A<LDW, 2>(X + (size_t)row0 * HH, W + (size_t)colw * LDW, acc, lane);
#pragma unroll
  for (int m = 0; m < 2; ++m)
#pragma unroll
    for (int nt = 0; nt < 2; ++nt)
#pragma unroll
      for (int rr = 0; rr < 4; ++rr) {
        int row = row0 + m * 16 + g * 4 + rr;
        out[(size_t)row * HH + colw + nt * 16 + c] = acc[m][nt][rr];
      }
}

// ---------------- phase A: layer-1 of both message MLPs, relu, reductions ----------------
__global__ __launch_bounds__(512) void phaseA_kernel(
    const float* __restrict__ e, const float* __restrict__ p_ap,
    const float* __restrict__ p_ue,
    const bf16_t* __restrict__ wu1e, const bf16_t* __restrict__ wa1e,
    float* __restrict__ part, float* __restrict__ R_ap) {
  __shared__ bf16_t ebuf[2][32 * 256];
  const int blk = blockIdx.x;              // 512 blocks
  const int b = blk >> 3, lc = blk & 7;
  const int tid = threadIdx.x, w = tid >> 6, lane = tid & 63;
  const int colw = w * 32, c = lane & 15, g = lane >> 4;
  const int l0 = lc * LGRP;

  bf16x8 wU[2][8], wA[2][8];
#pragma unroll
  for (int nt = 0; nt < 2; ++nt)
#pragma unroll
    for (int ks = 0; ks < 8; ++ks) {
      size_t off = (size_t)(colw + nt * 16 + c) * 512 + ks * 32 + g * 8;
      wU[nt][ks] = *(const bf16x8*)(wu1e + off);
      wA[nt][ks] = *(const bf16x8*)(wa1e + off);
    }

  float pue[2][2][4];
#pragma unroll
  for (int m = 0; m < 2; ++m)
#pragma unroll
    for (int nt = 0; nt < 2; ++nt)
#pragma unroll
      for (int rr = 0; rr < 4; ++rr)
        pue[m][nt][rr] = p_ue[(size_t)(b * KK + m * 16 + g * 4 + rr) * HH + colw + nt * 16 + c];

  f32x4 accU[2][2];
  const f32x4 z4 = {0.f, 0.f, 0.f, 0.f};
#pragma unroll
  for (int m = 0; m < 2; ++m)
#pragma unroll
    for (int nt = 0; nt < 2; ++nt) accU[m][nt] = z4;

  f32x4 rs[4];
  ld_tile(e + (size_t)((b * LL + l0) * KK) * HH, tid, rs);
  wr_tile(ebuf[0], tid, rs);

  for (int li = 0; li < LGRP; ++li) {
    __syncthreads();                       // ebuf[li&1] ready; ebuf[(li+1)&1] readers done
    const int l = l0 + li;
    if (li + 1 < LGRP) ld_tile(e + (size_t)((b * LL + l + 1) * KK) * HH, tid, rs);

    f32x4 aU[2][2], aA[2][2];
#pragma unroll
    for (int nt = 0; nt < 2; ++nt) {
      float pa = p_ap[(size_t)(b * LL + l) * HH + colw + nt * 16 + c];
      f32x4 t = {pa, pa, pa, pa};
      aA[0][nt] = t; aA[1][nt] = t;
#pragma unroll
      for (int rr = 0; rr < 4; ++rr) {
        aU[0][nt][rr] = pue[0][nt][rr];
        aU[1][nt][rr] = pue[1][nt][rr];
      }
    }
    const bf16_t* eb = ebuf[li & 1];
    const int swz = (c & 7) << 4;
#pragma unroll
    for (int ks = 0; ks < 8; ++ks) {
      const int kb = (ks * 32 + g * 8) * 2;
      bf16x8 a0 = *(const bf16x8*)((const char*)eb + c * 512 + (kb ^ swz));
      bf16x8 a1 = *(const bf16x8*)((const char*)eb + (16 + c) * 512 + (kb ^ swz));
#pragma unroll
      for (int nt = 0; nt < 2; ++nt) {
        aU[0][nt] = __builtin_amdgcn_mfma_f32_16x16x32_bf16(a0, wU[nt][ks], aU[0][nt], 0, 0, 0);
        aU[1][nt] = __builtin_amdgcn_mfma_f32_16x16x32_bf16(a1, wU[nt][ks], aU[1][nt], 0, 0, 0);
        aA[0][nt] = __builtin_amdgcn_mfma_f32_16x16x32_bf16(a0, wA[nt][ks], aA[0][nt], 0, 0, 0);
        aA[1][nt] = __builtin_amdgcn_mfma_f32_16x16x32_bf16(a1, wA[nt][ks], aA[1][nt], 0, 0, 0);
      }
    }

    // u2a: relu + k-reduce -> R_ap[b,l,:]
#pragma unroll
    for (int nt = 0; nt < 2; ++nt) {
      float s = 0.f;
#pragma unroll
      for (int m = 0; m < 2; ++m)
#pragma unroll
        for (int rr = 0; rr < 4; ++rr) s += fmaxf(aU[m][nt][rr], 0.f);
      s += __shfl_xor(s, 16);
      s += __shfl_xor(s, 32);
      if (lane < 16)
        R_ap[(size_t)(b * LL + l) * HH + colw + nt * 16 + lane] = s;
    }
    // a2u: relu accumulate over l
#pragma unroll
    for (int m = 0; m < 2; ++m)
#pragma unroll
      for (int nt = 0; nt < 2; ++nt)
#pragma unroll
        for (int rr = 0; rr < 4; ++rr)
          accU[m][nt][rr] += fmaxf(aA[m][nt][rr], 0.f);

    if (li + 1 < LGRP) wr_tile(ebuf[(li + 1) & 1], tid, rs);
  }

#pragma unroll
  for (int m = 0; m < 2; ++m)
#pragma unroll
    for (int nt = 0; nt < 2; ++nt)
#pragma unroll
      for (int rr = 0; rr < 4; ++rr) {
        int krow = m * 16 + g * 4 + rr;
        part[(size_t)((lc * BB + b) * KK + krow) * HH + colw + nt * 16 + c] = accU[m][nt][rr];
      }
}

// ---------------- reduce partials -> R_ue (Σ_l relu; /L folded in wa2s) ----------------
__global__ __launch_bounds__(256) void reduce_kernel(
    const float* __restrict__ part, float* __restrict__ R_ue) {
  int i = blockIdx.x * 256 + threadIdx.x;
  float s = 0.f;
#pragma unroll
  for (int lc = 0; lc < 8; ++lc) s += part[(size_t)lc * 524288 + i];
  R_ue[i] = s;
}

// ======== node2: m-GEMM + GRU + q-GEMM fused (all B operands bf16) — R13-proven ========
__global__ __launch_bounds__(256) void node2_kernel(
    const float* __restrict__ R_ue, const float* __restrict__ R_ap,
    const bf16_t* __restrict__ wa2s, const float* __restrict__ a2u_b2,
    const bf16_t* __restrict__ wu2s, const float* __restrict__ u2a_b2,
    const float* __restrict__ h_ue, const bf16_t* __restrict__ wih_ue,
    const float* __restrict__ ue_bih, const bf16_t* __restrict__ whh_ue,
    const float* __restrict__ ue_bhh,
    const float* __restrict__ h_ap, const bf16_t* __restrict__ wih_ap,
    const float* __restrict__ ap_bih, const bf16_t* __restrict__ whh_ap,
    const float* __restrict__ ap_bhh,
    const bf16_t* __restrict__ wed1, const float* __restrict__ ed_b1,
    float* __restrict__ hue_new, float* __restrict__ hap_new,
    float* __restrict__ q_ue, float* __restrict__ q_ap) {
  __shared__ bf16_t mbuf[32 * 256];
  __shared__ bf16_t hbuf[32 * 256];
  const int blk = blockIdx.x;
  const bool ue = blk < 64;
  const int row0 = ue ? blk * 32 : (blk - 64) * 32;
  const int tid = threadIdx.x, w = tid >> 6, lane = tid & 63;
  const int colw = w * 64, c = lane & 15, g = lane >> 4;
  const float*  R   = ue ? R_ue : R_ap;
  const bf16_t* W2  = ue ? wa2s : wu2s;
  const float*  b2  = ue ? a2u_b2 : u2a_b2;
  const float*  h   = ue ? h_ue : h_ap;
  const bf16_t* wih = ue ? wih_ue : wih_ap;
  const bf16_t* whh = ue ? whh_ue : whh_ap;
  const float*  bih = ue ? ue_bih : ap_bih;
  const float*  bhh = ue ? ue_bhh : ap_bhh;
  float* hout = ue ? hue_new : hap_new;
  float* qout = ue ? q_ue : q_ap;
  const bf16_t* wq = wed1 + (ue ? 0 : 256);   // Wed1[:, :H] vs Wed1[:, H:2H]

  // ---- stage 1: m = R*(W2*sc)^T + b2 -> mbuf (swizzled bf16) ----
  f32x4 acc[2][4];
#pragma unroll
  for (int nt = 0; nt < 4; ++nt) {
    float bv = b2[colw + nt * 16 + c];
    f32x4 t = {bv, bv, bv, bv};
    acc[0][nt] = t; acc[1][nt] = t;
  }
  mm_f32A<256, 4>(R + (size_t)row0 * HH, W2 + (size_t)colw * 256, acc, lane);
#pragma unroll
  for (int m = 0; m < 2; ++m)
#pragma unroll
    for (int nt = 0; nt < 4; ++nt)
#pragma unroll
      for (int rr = 0; rr < 4; ++rr) {
        int row = m * 16 + g * 4 + rr;
        int col = colw + nt * 16 + c;
        int off = row * 512 + ((col * 2) ^ ((row & 7) << 4));
        *(bf16_t*)((char*)mbuf + off) = (__bf16)acc[m][nt][rr];
      }
  __syncthreads();

  // ---- stage 2: GRU (x from mbuf LDS, h from global, weights bf16) ----
  f32x4 aR[2][4], aZ[2][4], aN[2][4], aHN[2][4];
#pragma unroll
  for (int nt = 0; nt < 4; ++nt) {
    int col = colw + nt * 16 + c;
    float vR = bih[col] + bhh[col];
    float vZ = bih[256 + col] + bhh[256 + col];
    float vN = bih[512 + col];
    float vH = bhh[512 + col];
    f32x4 tR = {vR, vR, vR, vR}, tZ = {vZ, vZ, vZ, vZ};
    f32x4 tN = {vN, vN, vN, vN}, tH = {vH, vH, vH, vH};
    aR[0][nt] = tR; aR[1][nt] = tR;
    aZ[0][nt] = tZ; aZ[1][nt] = tZ;
    aN[0][nt] = tN; aN[1][nt] = tN;
    aHN[0][nt] = tH; aHN[1][nt] = tH;
  }
  const float* Hp = h + (size_t)row0 * HH;
  mm_ldsA<256, 4>(mbuf, wih + (size_t)(0   + colw) * 256, aR, lane);
  mm_f32A<256, 4>(Hp,  whh + (size_t)(0   + colw) * 256, aR, lane);
  mm_ldsA<256, 4>(mbuf, wih + (size_t)(256 + colw) * 256, aZ, lane);
  mm_f32A<256, 4>(Hp,  whh + (size_t)(256 + colw) * 256, aZ, lane);
  mm_ldsA<256, 4>(mbuf, wih + (size_t)(512 + colw) * 256, aN, lane);
  mm_f32A<256, 4>(Hp,  whh + (size_t)(512 + colw) * 256, aHN, lane);
#pragma unroll
  for (int m = 0; m < 2; ++m)
#pragma unroll
    for (int nt = 0; nt < 4; ++nt)
#pragma unroll
      for (int rr = 0; rr < 4; ++rr) {
        int row = m * 16 + g * 4 + rr;
        int col = colw + nt * 16 + c;
        float rg = 1.f / (1.f + __expf(-aR[m][nt][rr]));
        float zg = 1.f / (1.f + __expf(-aZ[m][nt][rr]));
        float tv = aN[m][nt][rr] + rg * aHN[m][nt][rr];
        tv = fminf(fmaxf(tv, -15.f), 15.f);
        float ex = __expf(-2.f * tv);
        float ng = (1.f - ex) / (1.f + ex);
        float ho = h[(size_t)(row0 + row) * HH + col];
        float hn = (1.f - zg) * ng + zg * ho;
        hout[(size_t)(row0 + row) * HH + col] = hn;
        int off = row * 512 + ((col * 2) ^ ((row & 7) << 4));
        *(bf16_t*)((char*)hbuf + off) = (__bf16)hn;
      }
  __syncthreads();

  // ---- stage 3: q = h_new(LDS) * Wed1_part^T (+ ed_b1 for UE) ----
  f32x4 aq[2][4];
#pragma unroll
  for (int nt = 0; nt < 4; ++nt) {
    float bv = ue ? ed_b1[colw + nt * 16 + c] : 0.f;
    f32x4 t = {bv, bv, bv, bv};
    aq[0][nt] = t; aq[1][nt] = t;
  }
  mm_ldsA<768, 4>(hbuf, wq + (size_t)colw * 768, aq, lane);
#pragma unroll
  for (int m = 0; m < 2; ++m)
#pragma unroll
    for (int nt = 0; nt < 4; ++nt)
#pragma unroll
      for (int rr = 0; rr < 4; ++rr) {
        int row = row0 + m * 16 + g * 4 + rr;
        qout[(size_t)row * HH + colw + nt * 16 + c] = aq[m][nt][rr];
      }
}

// ---------------- phase C: edge update, software-pipelined two-GEMM chain (R11) ----------------
__global__ __launch_bounds__(512) void phaseC_kernel(
    const float* __restrict__ e, const float* __restrict__ q_ue,
    const float* __restrict__ q_ap,
    const bf16_t* __restrict__ wed1e, const bf16_t* __restrict__ wed2,
    const float* __restrict__ ed_b2, float* __restrict__ e_new) {
  __shared__ bf16_t ebuf[2][32 * 256];
  __shared__ bf16_t pbuf[2][32 * 256];
  const int blk = blockIdx.x;              // 512 blocks
  const int b = blk >> 3, lc = blk & 7;
  const int tid = threadIdx.x, w = tid >> 6, lane = tid & 63;
  const int colw = w * 32, c = lane & 15, g = lane >> 4;
  const int l0 = lc * LGRP;

  bf16x8 w1[2][8], w2[2][8];
#pragma unroll
  for (int nt = 0; nt < 2; ++nt)
#pragma unroll
    for (int ks = 0; ks < 8; ++ks) {
      w1[nt][ks] = *(const bf16x8*)(wed1e + (size_t)(colw + nt * 16 + c) * 768 + ks * 32 + g * 8);
      w2[nt][ks] = *(const bf16x8*)(wed2  + (size_t)(colw + nt * 16 + c) * 256 + ks * 32 + g * 8);
    }

  float qU[2][2][4];
#pragma unroll
  for (int m = 0; m < 2; ++m)
#pragma unroll
    for (int nt = 0; nt < 2; ++nt)
#pragma unroll
      for (int rr = 0; rr < 4; ++rr)
        qU[m][nt][rr] = q_ue[(size_t)(b * KK + m * 16 + g * 4 + rr) * HH + colw + nt * 16 + c];
  float b2v[2];
#pragma unroll
  for (int nt = 0; nt < 2; ++nt) b2v[nt] = ed_b2[colw + nt * 16 + c];

  const int swz = (c & 7) << 4;

  f32x4 rs[4];
  ld_tile(e + (size_t)((b * LL + l0) * KK) * HH, tid, rs);
  wr_tile(ebuf[0], tid, rs);

  for (int li = 0; li < LGRP; ++li) {
    __syncthreads();   // ebuf[li&1] + pbuf[(li-1)&1] ready; pbuf[li&1]/ebuf[(li+1)&1] readers done
    const int l = l0 + li;
    if (li + 1 < LGRP) ld_tile(e + (size_t)((b * LL + l + 1) * KK) * HH, tid, rs);

    // ---- layer-2 for tile li-1 (pbuf[(li-1)&1]) -> e_new[l-1] ----
    if (li > 0) {
      const bf16_t* pb = pbuf[(li - 1) & 1];
      f32x4 a2[2][2];
#pragma unroll
      for (int nt = 0; nt < 2; ++nt) {
        f32x4 t = {b2v[nt], b2v[nt], b2v[nt], b2v[nt]};
        a2[0][nt] = t; a2[1][nt] = t;
      }
#pragma unroll
      for (int ks = 0; ks < 8; ++ks) {
        const int kb = (ks * 32 + g * 8) * 2;
        bf16x8 a0 = *(const bf16x8*)((const char*)pb + c * 512 + (kb ^ swz));
        bf16x8 a1f = *(const bf16x8*)((const char*)pb + (16 + c) * 512 + (kb ^ swz));
#pragma unroll
        for (int nt = 0; nt < 2; ++nt) {
          a2[0][nt] = __builtin_amdgcn_mfma_f32_16x16x32_bf16(a0,  w2[nt][ks], a2[0][nt], 0, 0, 0);
          a2[1][nt] = __builtin_amdgcn_mfma_f32_16x16x32_bf16(a1f, w2[nt][ks], a2[1][nt], 0, 0, 0);
        }
      }
#pragma unroll
      for (int m = 0; m < 2; ++m)
#pragma unroll
        for (int nt = 0; nt < 2; ++nt)
#pragma unroll
          for (int rr = 0; rr < 4; ++rr) {
            int row = m * 16 + g * 4 + rr;
            int col = colw + nt * 16 + c;
            e_new[(size_t)((b * LL + l - 1) * KK + row) * HH + col] = a2[m][nt][rr];
          }
    }

    // ---- layer-1 for tile li (ebuf[li&1]) -> relu -> pbuf[li&1] ----
    f32x4 a1[2][2];
#pragma unroll
    for (int nt = 0; nt < 2; ++nt) {
      float qa = q_ap[(size_t)(b * LL + l) * HH + colw + nt * 16 + c];
#pragma unroll
      for (int rr = 0; rr < 4; ++rr) {
        a1[0][nt][rr] = qa + qU[0][nt][rr];
        a1[1][nt][rr] = qa + qU[1][nt][rr];
      }
    }
    const bf16_t* eb = ebuf[li & 1];
#pragma unroll
    for (int ks = 0; ks < 8; ++ks) {
      const int kb = (ks * 32 + g * 8) * 2;
      bf16x8 a0 = *(const bf16x8*)((const char*)eb + c * 512 + (kb ^ swz));
      bf16x8 a1f = *(const bf16x8*)((const char*)eb + (16 + c) * 512 + (kb ^ swz));
#pragma unroll
      for (int nt = 0; nt < 2; ++nt) {
        a1[0][nt] = __builtin_amdgcn_mfma_f32_16x16x32_bf16(a0,  w1[nt][ks], a1[0][nt], 0, 0, 0);
        a1[1][nt] = __builtin_amdgcn_mfma_f32_16x16x32_bf16(a1f, w1[nt][ks], a1[1][nt], 0, 0, 0);
      }
    }
    bf16_t* pw = pbuf[li & 1];
#pragma unroll
    for (int m = 0; m < 2; ++m)
#pragma unroll
      for (int nt = 0; nt < 2; ++nt)
#pragma unroll
        for (int rr = 0; rr < 4; ++rr) {
          int row = m * 16 + g * 4 + rr;
          int col = colw + nt * 16 + c;
          float v = fmaxf(a1[m][nt][rr], 0.f);
          int off = row * 512 + ((col * 2) ^ ((row & 7) << 4));
          *(bf16_t*)((char*)pw + off) = (__bf16)v;
        }

    if (li + 1 < LGRP) wr_tile(ebuf[(li + 1) & 1], tid, rs);
  }

  // ---- epilogue: layer-2 for the last tile ----
  __syncthreads();
  {
    const bf16_t* pb = pbuf[(LGRP - 1) & 1];
    f32x4 a2[2][2];
#pragma unroll
    for (int nt = 0; nt < 2; ++nt) {
      f32x4 t = {b2v[nt], b2v[nt], b2v[nt], b2v[nt]};
      a2[0][nt] = t; a2[1][nt] = t;
    }
#pragma unroll
    for (int ks = 0; ks < 8; ++ks) {
      const int kb = (ks * 32 + g * 8) * 2;
      bf16x8 a0 = *(const bf16x8*)((const char*)pb + c * 512 + (kb ^ swz));
      bf16x8 a1f = *(const bf16x8*)((const char*)pb + (16 + c) * 512 + (kb ^ swz));
#pragma unroll
      for (int nt = 0; nt < 2; ++nt) {
        a2[0][nt] = __builtin_amdgcn_mfma_f32_16x16x32_bf16(a0,  w2[nt][ks], a2[0][nt], 0, 0, 0);
        a2[1][nt] = __builtin_amdgcn_mfma_f32_16x16x32_bf16(a1f, w2[nt][ks], a2[1][nt], 0, 0, 0);
      }
    }
#pragma unroll
    for (int m = 0; m < 2; ++m)
#pragma unroll
      for (int nt = 0; nt < 2; ++nt)
#pragma unroll
        for (int rr = 0; rr < 4; ++rr) {
          int row = m * 16 + g * 4 + rr;
          int col = colw + nt * 16 + c;
          e_new[(size_t)((b * LL + l0 + LGRP - 1) * KK + row) * HH + col] = a2[m][nt][rr];
        }
  }
}

extern "C" void kernel_launch(void* const* d_in, const int* in_sizes, int n_in,
                              void* d_out, int out_size, void* d_ws, size_t ws_size,
                              hipStream_t stream) {
  const float* h_ue   = (const float*)d_in[0];
  const float* h_ap   = (const float*)d_in[1];
  const float* e      = (const float*)d_in[2];
  const float* a2u_w1 = (const float*)d_in[3];
  const float* a2u_b1 = (const float*)d_in[4];
  const float* a2u_w2 = (const float*)d_in[5];
  const float* a2u_b2 = (const float*)d_in[6];
  const float* u2a_w1 = (const float*)d_in[7];
  const float* u2a_b1 = (const float*)d_in[8];
  const float* u2a_w2 = (const float*)d_in[9];
  const float* u2a_b2 = (const float*)d_in[10];
  const float* ue_wih = (const float*)d_in[11];
  const float* ue_bih = (const float*)d_in[12];
  const float* ue_whh = (const float*)d_in[13];
  const float* ue_bhh = (const float*)d_in[14];
  const float* ap_wih = (const float*)d_in[15];
  const float* ap_bih = (const float*)d_in[16];
  const float* ap_whh = (const float*)d_in[17];
  const float* ap_bhh = (const float*)d_in[18];
  const float* ed_w1  = (const float*)d_in[19];
  const float* ed_b1  = (const float*)d_in[20];
  const float* ed_w2  = (const float*)d_in[21];
  const float* ed_b2  = (const float*)d_in[22];

  // workspace layout (bf16 weights, then f32 scratch)
  bf16_t* wb      = (bf16_t*)d_ws;
  bf16_t* wa1     = wb;                 // a2u_w1 (256x512)
  bf16_t* wa2s    = wa1 + 131072;       // a2u_w2 / 64
  bf16_t* wu1     = wa2s + 65536;       // u2a_w1 (256x512)
  bf16_t* wu2s    = wu1 + 131072;       // u2a_w2 / 32
  bf16_t* wih_ue  = wu2s + 65536;
  bf16_t* whh_ue  = wih_ue + 196608;
  bf16_t* wih_ap  = whh_ue + 196608;
  bf16_t* whh_ap  = wih_ap + 196608;
  bf16_t* wed1    = whh_ap + 196608;    // ed_w1 (256x768)
  bf16_t* wed2    = wed1 + 196608;      // ed_w2 (256x256)
  float* fbase = (float*)((char*)d_ws + 2883584);
  float* m_ue = fbase;                  // R_ue slot
  float* m_ap = m_ue + 524288;
  float* p_ap = m_ap + 1048576;         // 1048576
  float* p_ue = p_ap + 1048576;         // 524288
  float* q_ue = p_ue + 524288;          // 524288
  float* q_ap = q_ue + 524288;          // 1048576 (aliased: R_ap before node2)
  float* part = q_ap + 1048576;         // 8 * 524288
  float* R_ue = m_ue;                   // reduce writes here; node2 reads
  float* R_ap = q_ap;                   // node2 reads R_ap rows (stage 1), writes q_ap rows (stage 3) — safe

  float* out      = (float*)d_out;
  float* hue_new  = out;                // 524288
  float* hap_new  = out + 524288;       // 1048576
  float* e_new    = out + 1572864;      // 33554432

  prep_kernel<<<5632, 256, 0, stream>>>(a2u_w1, a2u_w2, u2a_w1, u2a_w2,
                                        ue_wih, ue_whh, ap_wih, ap_whh,
                                        ed_w1, ed_w2, wb);
  // p_ap = h_ap*Wa1_h^T + b1 ; p_ue = h_ue*Wu1_h^T + b1
  proj2h_kernel<512><<<384, 256, 0, stream>>>(h_ap, wa1, a2u_b1, p_ap, 128,
                                              h_ue, wu1, u2a_b1, p_ue);
  phaseA_kernel<<<512, 512, 0, stream>>>(e, p_ap, p_ue, wu1 + 256, wa1 + 256,
                                         part, R_ap);
  reduce_kernel<<<2048, 256, 0, stream>>>(part, R_ue);
  node2_kernel<<<192, 256, 0, stream>>>(R_ue, R_ap,
                                        wa2s, a2u_b2, wu2s, u2a_b2,
                                        h_ue, wih_ue, ue_bih, whh_ue, ue_bhh,
                                        h_ap, wih_ap, ap_bih, whh_ap, ap_bhh,
                                        wed1, ed_b1,
                                        hue_new, hap_new, q_ue, q_ap);
  phaseC_kernel<<<512, 512, 0, stream>>>(e, q_ue, q_ap, wed1 + 512, wed2, ed_b2, e_new);
}